// Round 6
// baseline (246.294 us; speedup 1.0000x reference)
//
#include <hip/hip_runtime.h>
#include <math.h>

// ContrastiveLoss: B=16384, D=64, fp32 in, scalar fp32 out.
// loss_i = logsumexp_j(sim[i,j]) - sim[i,i];  out = mean_i(loss_i)
// sim = normalize_rows(A) @ normalize_rows(B)^T / 0.07
//
// Round 6: 128 A-rows per wave (8 MFMA row-tiles). The exp2 trans-pipe is the
// hard floor (~27us chip-wide for 268M v_exp_f32 at 16cyc/wave-instr); round 5
// sat at 2.4x that because each wave's trans duty cycle was ~50% and only ~3
// waves/SIMD were resident. Doubling rows/wave doubles trans work per ds_read
// iteration (256->512 cyc) -> duty ~80%, so 3 waves/SIMD saturate the pipe.
// Staging (unchanged, validated swizzle) is now amortized over 2x output rows.

#define NROWS 16384
#define DIM 64
#define INV_T 14.285714285714286f           // 1/0.07
#define LOG2E 1.44269504088896340736f
#define LN2   0.69314718055994530942f
#define SCALE (INV_T * LOG2E)               // fold 1/T and log2(e) into A

#define JC     64                           // j-chunks; == wavefront size
#define JPC    (NROWS / JC)                 // 256 j per chunk
#define NTILES (JPC / 16)                   // 16 B-tiles per chunk
#define TT     8                            // A row-tiles per wave (128 rows)
#define WR     (TT * 16)                    // 128 rows per wave
#define BROWS  (4 * WR)                     // 512 rows per block (4 waves)
#define ROWB   (DIM * 2)                    // 128 bytes per bf16 row
#define LDSB   (JPC * ROWB)                 // 32 KiB

typedef __attribute__((ext_vector_type(8))) short bf16x8;  // 8 bf16 = 4 VGPRs
typedef __attribute__((ext_vector_type(4))) float f32x4;

static __device__ __forceinline__ unsigned short f2bf(float f) {
    unsigned int u = __float_as_uint(f);
    unsigned int r = (u + 0x7fffu + ((u >> 16) & 1u)) >> 16;   // RNE
    return (unsigned short)r;
}

// ------- kernel 1: normalize rows of BOTH inputs -> bf16 (A pre-scaled) ----
__global__ __launch_bounds__(256) void nrm_bf16_kernel(
        const float* __restrict__ A, const float* __restrict__ B,
        unsigned short* __restrict__ Ab, unsigned short* __restrict__ Bb) {
    int wid  = (blockIdx.x * 256 + threadIdx.x) >> 6;   // 0..2*NROWS-1
    int lane = threadIdx.x & 63;
    const float* in;
    unsigned short* out;
    float scale;
    int row;
    if (wid < NROWS) { in = A; out = Ab; scale = SCALE; row = wid; }
    else             { in = B; out = Bb; scale = 1.0f;  row = wid - NROWS; }
    float x  = in[row * DIM + lane];
    float ss = x * x;
    #pragma unroll
    for (int m = 32; m >= 1; m >>= 1) ss += __shfl_xor(ss, m, 64);
    out[row * DIM + lane] = f2bf(x * rsqrtf(ss) * scale);
}

// -------- kernel 2: LDS-staged MFMA sim tiles + exp2 row-sum partials ------
__global__ __launch_bounds__(256, 3) void simexp_kernel(
        const unsigned short* __restrict__ Ab,
        const unsigned short* __restrict__ Bb,
        float* __restrict__ partials) {
    __shared__ __align__(1024) unsigned char lds[LDSB];
    const int lane = threadIdx.x & 63;
    const int wid  = threadIdx.x >> 6;                  // wave in block
    const int jc   = blockIdx.x & (JC - 1);
    const int rb   = blockIdx.x / JC;
    const int i0   = rb * BROWS + wid * WR;             // wave's first A row
    const int lr   = lane & 15;                         // fragment row/col
    const int lk   = lane >> 4;                         // k-group (x8 bf16)

    // ---- stage B chunk: linear LDS dest, XOR-permuted global source ------
    // LDS(row, col16) holds global(row, col16 ^ (row&7)); each instr covers
    // 8 rows (1 KiB), so row&7 == lane>>3 inside the instr.  (validated r5)
    const unsigned char* gB = (const unsigned char*)Bb + (size_t)jc * JPC * ROWB;
    const int perm = ((lane >> 3) << 7) | ((((lane & 7) ^ (lane >> 3))) << 4);
    #pragma unroll
    for (int i = 0; i < 8; ++i) {
        const int off = (wid * 8 + i) * 1024;           // wave's 8 slabs
        __builtin_amdgcn_global_load_lds(
            (const __attribute__((address_space(1))) void*)(gB + off + perm),
            (__attribute__((address_space(3))) void*)(&lds[off]),
            16, 0, 0);
    }

    // ---- A fragments (global/L2 loads overlap the staging latency) -------
    bf16x8 a[TT][2];
    #pragma unroll
    for (int t = 0; t < TT; ++t) {
        const unsigned short* ap = Ab + (size_t)(i0 + t * 16 + lr) * DIM + lk * 8;
        a[t][0] = *(const bf16x8*)(ap);
        a[t][1] = *(const bf16x8*)(ap + 32);
    }

    float es[TT][4];
    #pragma unroll
    for (int t = 0; t < TT; ++t)
        #pragma unroll
        for (int r = 0; r < 4; ++r) es[t][r] = 0.0f;

    __syncthreads();                                    // staging complete

    // ds_read bases: row lr, col16 = lk (frag0) / lk^4 (frag1), un-swizzled
    // via the same XOR; loop-invariant since row&7 == lr&7 for every tile.
    const unsigned char* lp0 = &lds[lr * ROWB + (((lk    ) ^ (lr & 7)) << 4)];
    const unsigned char* lp1 = &lds[lr * ROWB + (((lk ^ 4) ^ (lr & 7)) << 4)];

    const f32x4 zero = {0.f, 0.f, 0.f, 0.f};

    for (int jt = 0; jt < NTILES; ++jt) {
        bf16x8 n0 = *(const bf16x8*)(lp0 + jt * (16 * ROWB));
        bf16x8 n1 = *(const bf16x8*)(lp1 + jt * (16 * ROWB));
        #pragma unroll
        for (int t = 0; t < TT; ++t) {
            f32x4 acc = __builtin_amdgcn_mfma_f32_16x16x32_bf16(a[t][0], n0, zero, 0, 0, 0);
            acc = __builtin_amdgcn_mfma_f32_16x16x32_bf16(a[t][1], n1, acc, 0, 0, 0);
            #pragma unroll
            for (int r = 0; r < 4; ++r)
                es[t][r] += __builtin_amdgcn_exp2f(acc[r]);
        }
    }

    // es[t][r]: partial over this lane's 16-col slice of row i0+t*16+lk*4+r.
    #pragma unroll
    for (int t = 0; t < TT; ++t)
        #pragma unroll
        for (int r = 0; r < 4; ++r) {
            float v = es[t][r];
            v += __shfl_xor(v, 1, 64);
            v += __shfl_xor(v, 2, 64);
            v += __shfl_xor(v, 4, 64);
            v += __shfl_xor(v, 8, 64);
            es[t][r] = v;
        }

    if (lr == 0) {                                      // lanes 0,16,32,48
        float* pout = partials + (size_t)jc * NROWS + i0;
        #pragma unroll
        for (int t = 0; t < TT; ++t) {
            f32x4 v = {es[t][0], es[t][1], es[t][2], es[t][3]};
            *(f32x4*)(pout + t * 16 + lk * 4) = v;      // rows lk*4..lk*4+3
        }
    }
}

// -------- kernel 3: per-row loss; lane-parallel partial sum (JC==64) -------
__global__ __launch_bounds__(256) void rowloss_kernel(
        const float* __restrict__ A, const float* __restrict__ B,
        const float* __restrict__ partials, float* __restrict__ rowloss) {
    int row  = (blockIdx.x * 256 + threadIdx.x) >> 6;
    int lane = threadIdx.x & 63;
    float a = A[row * DIM + lane];
    float b = B[row * DIM + lane];
    float saa = a * a, sbb = b * b, sab = a * b;
    float S   = partials[(size_t)lane * NROWS + row];   // one chunk per lane
    #pragma unroll
    for (int m = 32; m >= 1; m >>= 1) {
        saa += __shfl_xor(saa, m, 64);
        sbb += __shfl_xor(sbb, m, 64);
        sab += __shfl_xor(sab, m, 64);
        S   += __shfl_xor(S,   m, 64);
    }
    if (lane == 0) {
        float diag = sab * rsqrtf(saa * sbb);           // exact fp32 cos-sim
        rowloss[row] = LN2 * __builtin_amdgcn_logf(S) - diag * INV_T;
    }
}

// -------- kernel 4: deterministic mean over 16384 row losses ---------------
__global__ __launch_bounds__(1024) void mean_kernel(
        const float* __restrict__ rowloss, float* __restrict__ out) {
    float s = 0.f;
    for (int idx = threadIdx.x; idx < NROWS; idx += 1024) s += rowloss[idx];
    __shared__ float red[16];
    #pragma unroll
    for (int m = 32; m >= 1; m >>= 1) s += __shfl_xor(s, m, 64);
    if ((threadIdx.x & 63) == 0) red[threadIdx.x >> 6] = s;
    __syncthreads();
    if (threadIdx.x < 16) {
        float t = red[threadIdx.x];
        #pragma unroll
        for (int m = 8; m >= 1; m >>= 1) t += __shfl_xor(t, m, 16);
        if (threadIdx.x == 0) out[0] = t * (1.0f / NROWS);
    }
}

extern "C" void kernel_launch(void* const* d_in, const int* in_sizes, int n_in,
                              void* d_out, int out_size, void* d_ws, size_t ws_size,
                              hipStream_t stream) {
    const float* A  = (const float*)d_in[0];
    const float* Bm = (const float*)d_in[1];
    float* out = (float*)d_out;

    unsigned short* Ab = (unsigned short*)d_ws;                 // 2 MiB
    unsigned short* Bb = Ab + (size_t)NROWS * DIM;              // 2 MiB
    float* partials    = (float*)(Bb + (size_t)NROWS * DIM);    // 4 MiB
    float* rowloss     = partials + (size_t)JC * NROWS;         // 64 KiB

    nrm_bf16_kernel<<<2 * NROWS / 4, 256, 0, stream>>>(A, Bm, Ab, Bb);
    simexp_kernel<<<(NROWS / BROWS) * JC, 256, 0, stream>>>(Ab, Bb, partials);
    rowloss_kernel<<<NROWS / 4, 256, 0, stream>>>(A, Bm, partials, rowloss);
    mean_kernel<<<1, 1024, 0, stream>>>(rowloss, out);
}

// Round 7
// 94.971 us; speedup vs baseline: 2.5934x; 2.5934x over previous
//
#include <hip/hip_runtime.h>
#include <math.h>

// ContrastiveLoss: B=16384, D=64, fp32 in, scalar fp32 out.
// loss_i = logsumexp_j(sim[i,j]) - sim[i,i];  out = mean_i(loss_i)
// sim = normalize_rows(A) @ normalize_rows(B)^T / 0.07
//
// Round 7: TT=8 (128 A-rows/wave) re-run WITHOUT the __launch_bounds__ min-
// waves arg. Round 6's (256,3) made hipcc allocate 84 VGPR and spill a[]/es[]
// to scratch (WRITE_SIZE 675MB, 246us). Uncapped, the compiler allocates what
// the kernel needs (~150-170) at 3 waves/SIMD; per-wave trans duty ~0.8
// (512cyc exp2 vs ~90cyc MFMA+ds per B-tile), so 3 waves saturate the exp2
// trans pipe whose chip-wide floor is ~27us for 268M v_exp_f32.

#define NROWS 16384
#define DIM 64
#define INV_T 14.285714285714286f           // 1/0.07
#define LOG2E 1.44269504088896340736f
#define LN2   0.69314718055994530942f
#define SCALE (INV_T * LOG2E)               // fold 1/T and log2(e) into A

#define JC     64                           // j-chunks; == wavefront size
#define JPC    (NROWS / JC)                 // 256 j per chunk
#define NTILES (JPC / 16)                   // 16 B-tiles per chunk
#define TT     8                            // A row-tiles per wave (128 rows)
#define WR     (TT * 16)                    // 128 rows per wave
#define BROWS  (4 * WR)                     // 512 rows per block (4 waves)
#define ROWB   (DIM * 2)                    // 128 bytes per bf16 row
#define LDSB   (JPC * ROWB)                 // 32 KiB

typedef __attribute__((ext_vector_type(8))) short bf16x8;  // 8 bf16 = 4 VGPRs
typedef __attribute__((ext_vector_type(4))) float f32x4;

static __device__ __forceinline__ unsigned short f2bf(float f) {
    unsigned int u = __float_as_uint(f);
    unsigned int r = (u + 0x7fffu + ((u >> 16) & 1u)) >> 16;   // RNE
    return (unsigned short)r;
}

// ------- kernel 1: normalize rows of BOTH inputs -> bf16 (A pre-scaled) ----
__global__ __launch_bounds__(256) void nrm_bf16_kernel(
        const float* __restrict__ A, const float* __restrict__ B,
        unsigned short* __restrict__ Ab, unsigned short* __restrict__ Bb) {
    int wid  = (blockIdx.x * 256 + threadIdx.x) >> 6;   // 0..2*NROWS-1
    int lane = threadIdx.x & 63;
    const float* in;
    unsigned short* out;
    float scale;
    int row;
    if (wid < NROWS) { in = A; out = Ab; scale = SCALE; row = wid; }
    else             { in = B; out = Bb; scale = 1.0f;  row = wid - NROWS; }
    float x  = in[row * DIM + lane];
    float ss = x * x;
    #pragma unroll
    for (int m = 32; m >= 1; m >>= 1) ss += __shfl_xor(ss, m, 64);
    out[row * DIM + lane] = f2bf(x * rsqrtf(ss) * scale);
}

// -------- kernel 2: LDS-staged MFMA sim tiles + exp2 row-sum partials ------
__global__ __launch_bounds__(256) void simexp_kernel(
        const unsigned short* __restrict__ Ab,
        const unsigned short* __restrict__ Bb,
        float* __restrict__ partials) {
    __shared__ __align__(1024) unsigned char lds[LDSB];
    const int lane = threadIdx.x & 63;
    const int wid  = threadIdx.x >> 6;                  // wave in block
    const int jc   = blockIdx.x & (JC - 1);
    const int rb   = blockIdx.x / JC;
    const int i0   = rb * BROWS + wid * WR;             // wave's first A row
    const int lr   = lane & 15;                         // fragment row/col
    const int lk   = lane >> 4;                         // k-group (x8 bf16)

    // ---- stage B chunk: linear LDS dest, XOR-permuted global source ------
    // LDS(row, col16) holds global(row, col16 ^ (row&7)); each instr covers
    // 8 rows (1 KiB), so row&7 == lane>>3 inside the instr.  (validated r5)
    const unsigned char* gB = (const unsigned char*)Bb + (size_t)jc * JPC * ROWB;
    const int perm = ((lane >> 3) << 7) | ((((lane & 7) ^ (lane >> 3))) << 4);
    #pragma unroll
    for (int i = 0; i < 8; ++i) {
        const int off = (wid * 8 + i) * 1024;           // wave's 8 slabs
        __builtin_amdgcn_global_load_lds(
            (const __attribute__((address_space(1))) void*)(gB + off + perm),
            (__attribute__((address_space(3))) void*)(&lds[off]),
            16, 0, 0);
    }

    // ---- A fragments (global/L2 loads overlap the staging latency) -------
    bf16x8 a[TT][2];
    #pragma unroll
    for (int t = 0; t < TT; ++t) {
        const unsigned short* ap = Ab + (size_t)(i0 + t * 16 + lr) * DIM + lk * 8;
        a[t][0] = *(const bf16x8*)(ap);
        a[t][1] = *(const bf16x8*)(ap + 32);
    }

    float es[TT][4];
    #pragma unroll
    for (int t = 0; t < TT; ++t)
        #pragma unroll
        for (int r = 0; r < 4; ++r) es[t][r] = 0.0f;

    __syncthreads();                                    // staging complete

    // ds_read bases: row lr, col16 = lk (frag0) / lk^4 (frag1), un-swizzled
    // via the same XOR; loop-invariant since row&7 == lr&7 for every tile.
    const unsigned char* lp0 = &lds[lr * ROWB + (((lk    ) ^ (lr & 7)) << 4)];
    const unsigned char* lp1 = &lds[lr * ROWB + (((lk ^ 4) ^ (lr & 7)) << 4)];

    const f32x4 zero = {0.f, 0.f, 0.f, 0.f};

    for (int jt = 0; jt < NTILES; ++jt) {
        bf16x8 n0 = *(const bf16x8*)(lp0 + jt * (16 * ROWB));
        bf16x8 n1 = *(const bf16x8*)(lp1 + jt * (16 * ROWB));
        #pragma unroll
        for (int t = 0; t < TT; ++t) {
            f32x4 acc = __builtin_amdgcn_mfma_f32_16x16x32_bf16(a[t][0], n0, zero, 0, 0, 0);
            acc = __builtin_amdgcn_mfma_f32_16x16x32_bf16(a[t][1], n1, acc, 0, 0, 0);
            #pragma unroll
            for (int r = 0; r < 4; ++r)
                es[t][r] += __builtin_amdgcn_exp2f(acc[r]);
        }
    }

    // es[t][r]: partial over this lane's 16-col slice of row i0+t*16+lk*4+r.
    #pragma unroll
    for (int t = 0; t < TT; ++t)
        #pragma unroll
        for (int r = 0; r < 4; ++r) {
            float v = es[t][r];
            v += __shfl_xor(v, 1, 64);
            v += __shfl_xor(v, 2, 64);
            v += __shfl_xor(v, 4, 64);
            v += __shfl_xor(v, 8, 64);
            es[t][r] = v;
        }

    if (lr == 0) {                                      // lanes 0,16,32,48
        float* pout = partials + (size_t)jc * NROWS + i0;
        #pragma unroll
        for (int t = 0; t < TT; ++t) {
            f32x4 v = {es[t][0], es[t][1], es[t][2], es[t][3]};
            *(f32x4*)(pout + t * 16 + lk * 4) = v;      // rows lk*4..lk*4+3
        }
    }
}

// -------- kernel 3: per-row loss; lane-parallel partial sum (JC==64) -------
__global__ __launch_bounds__(256) void rowloss_kernel(
        const float* __restrict__ A, const float* __restrict__ B,
        const float* __restrict__ partials, float* __restrict__ rowloss) {
    int row  = (blockIdx.x * 256 + threadIdx.x) >> 6;
    int lane = threadIdx.x & 63;
    float a = A[row * DIM + lane];
    float b = B[row * DIM + lane];
    float saa = a * a, sbb = b * b, sab = a * b;
    float S   = partials[(size_t)lane * NROWS + row];   // one chunk per lane
    #pragma unroll
    for (int m = 32; m >= 1; m >>= 1) {
        saa += __shfl_xor(saa, m, 64);
        sbb += __shfl_xor(sbb, m, 64);
        sab += __shfl_xor(sab, m, 64);
        S   += __shfl_xor(S,   m, 64);
    }
    if (lane == 0) {
        float diag = sab * rsqrtf(saa * sbb);           // exact fp32 cos-sim
        rowloss[row] = LN2 * __builtin_amdgcn_logf(S) - diag * INV_T;
    }
}

// -------- kernel 4: deterministic mean over 16384 row losses ---------------
__global__ __launch_bounds__(1024) void mean_kernel(
        const float* __restrict__ rowloss, float* __restrict__ out) {
    float s = 0.f;
    for (int idx = threadIdx.x; idx < NROWS; idx += 1024) s += rowloss[idx];
    __shared__ float red[16];
    #pragma unroll
    for (int m = 32; m >= 1; m >>= 1) s += __shfl_xor(s, m, 64);
    if ((threadIdx.x & 63) == 0) red[threadIdx.x >> 6] = s;
    __syncthreads();
    if (threadIdx.x < 16) {
        float t = red[threadIdx.x];
        #pragma unroll
        for (int m = 8; m >= 1; m >>= 1) t += __shfl_xor(t, m, 16);
        if (threadIdx.x == 0) out[0] = t * (1.0f / NROWS);
    }
}

extern "C" void kernel_launch(void* const* d_in, const int* in_sizes, int n_in,
                              void* d_out, int out_size, void* d_ws, size_t ws_size,
                              hipStream_t stream) {
    const float* A  = (const float*)d_in[0];
    const float* Bm = (const float*)d_in[1];
    float* out = (float*)d_out;

    unsigned short* Ab = (unsigned short*)d_ws;                 // 2 MiB
    unsigned short* Bb = Ab + (size_t)NROWS * DIM;              // 2 MiB
    float* partials    = (float*)(Bb + (size_t)NROWS * DIM);    // 4 MiB
    float* rowloss     = partials + (size_t)JC * NROWS;         // 64 KiB

    nrm_bf16_kernel<<<2 * NROWS / 4, 256, 0, stream>>>(A, Bm, Ab, Bb);
    simexp_kernel<<<(NROWS / BROWS) * JC, 256, 0, stream>>>(Ab, Bb, partials);
    rowloss_kernel<<<NROWS / 4, 256, 0, stream>>>(A, Bm, partials, rowloss);
    mean_kernel<<<1, 1024, 0, stream>>>(rowloss, out);
}

// Round 8
// 83.151 us; speedup vs baseline: 2.9620x; 1.1422x over previous
//
#include <hip/hip_runtime.h>
#include <math.h>

// ContrastiveLoss: B=16384, D=64, fp32 in, scalar fp32 out.
// loss_i = logsumexp_j(sim[i,j]) - sim[i,i];  out = mean_i(loss_i)
// sim = normalize_rows(A) @ normalize_rows(B)^T / 0.07
//
// Round 8: R5 engine (TT=4, LDS-staged B, validated XOR swizzle) on a
// register diet. Evidence R2/R5/R7: time ~ 1/(resident waves x per-wave
// duty); trans-pipe workload fixed (~27us floor). R5's per-wave duty ~30%
// (MFMA->exp RAW + ds latency bubbles) so RESIDENCY is the lever: drop the
// hand pipeline (it only inflated live ranges, R4 proved ordering is moot),
// and use 8-wave blocks sharing one 32KB chunk. Target VGPR <= ~105.

#define NROWS 16384
#define DIM 64
#define INV_T 14.285714285714286f           // 1/0.07
#define LOG2E 1.44269504088896340736f
#define LN2   0.69314718055994530942f
#define SCALE (INV_T * LOG2E)               // fold 1/T and log2(e) into A

#define JC     64                           // j-chunks; == wavefront size
#define JPC    (NROWS / JC)                 // 256 j per chunk
#define NTILES (JPC / 16)                   // 16 B-tiles per chunk
#define TT     4                            // A row-tiles per wave (64 rows)
#define WR     (TT * 16)                    // 64 rows per wave
#define NWAVE  8                            // waves per block
#define BROWS  (NWAVE * WR)                 // 512 rows per block
#define ROWB   (DIM * 2)                    // 128 bytes per bf16 row
#define LDSB   (JPC * ROWB)                 // 32 KiB

typedef __attribute__((ext_vector_type(8))) short bf16x8;  // 8 bf16 = 4 VGPRs
typedef __attribute__((ext_vector_type(4))) float f32x4;

static __device__ __forceinline__ unsigned short f2bf(float f) {
    unsigned int u = __float_as_uint(f);
    unsigned int r = (u + 0x7fffu + ((u >> 16) & 1u)) >> 16;   // RNE
    return (unsigned short)r;
}

// ------- kernel 1: normalize rows of BOTH inputs -> bf16 (A pre-scaled) ----
__global__ __launch_bounds__(256) void nrm_bf16_kernel(
        const float* __restrict__ A, const float* __restrict__ B,
        unsigned short* __restrict__ Ab, unsigned short* __restrict__ Bb) {
    int wid  = (blockIdx.x * 256 + threadIdx.x) >> 6;   // 0..2*NROWS-1
    int lane = threadIdx.x & 63;
    const float* in;
    unsigned short* out;
    float scale;
    int row;
    if (wid < NROWS) { in = A; out = Ab; scale = SCALE; row = wid; }
    else             { in = B; out = Bb; scale = 1.0f;  row = wid - NROWS; }
    float x  = in[row * DIM + lane];
    float ss = x * x;
    #pragma unroll
    for (int m = 32; m >= 1; m >>= 1) ss += __shfl_xor(ss, m, 64);
    out[row * DIM + lane] = f2bf(x * rsqrtf(ss) * scale);
}

// -------- kernel 2: LDS-staged MFMA sim tiles + exp2 row-sum partials ------
__global__ __launch_bounds__(NWAVE * 64) void simexp_kernel(
        const unsigned short* __restrict__ Ab,
        const unsigned short* __restrict__ Bb,
        float* __restrict__ partials) {
    __shared__ __align__(1024) unsigned char lds[LDSB];
    const int lane = threadIdx.x & 63;
    const int wid  = threadIdx.x >> 6;                  // wave in block
    const int jc   = blockIdx.x & (JC - 1);
    const int rb   = blockIdx.x / JC;
    const int i0   = rb * BROWS + wid * WR;             // wave's first A row
    const int lr   = lane & 15;                         // fragment row/col
    const int lk   = lane >> 4;                         // k-group (x8 bf16)

    // ---- stage B chunk: linear LDS dest, XOR-permuted global source ------
    // LDS(row, col16) holds global(row, col16 ^ (row&7)); each instr covers
    // 8 rows (1 KiB), so row&7 == lane>>3 inside the instr.  (validated r5)
    const unsigned char* gB = (const unsigned char*)Bb + (size_t)jc * JPC * ROWB;
    const int perm = ((lane >> 3) << 7) | ((((lane & 7) ^ (lane >> 3))) << 4);
    #pragma unroll
    for (int i = 0; i < LDSB / 1024 / NWAVE; ++i) {     // 4 slabs per wave
        const int off = (wid * (LDSB / 1024 / NWAVE) + i) * 1024;
        __builtin_amdgcn_global_load_lds(
            (const __attribute__((address_space(1))) void*)(gB + off + perm),
            (__attribute__((address_space(3))) void*)(&lds[off]),
            16, 0, 0);
    }

    // ---- A fragments (global/L2 loads overlap the staging latency) -------
    bf16x8 a[TT][2];
    #pragma unroll
    for (int t = 0; t < TT; ++t) {
        const unsigned short* ap = Ab + (size_t)(i0 + t * 16 + lr) * DIM + lk * 8;
        a[t][0] = *(const bf16x8*)(ap);
        a[t][1] = *(const bf16x8*)(ap + 32);
    }

    float es[TT][4];
    #pragma unroll
    for (int t = 0; t < TT; ++t)
        #pragma unroll
        for (int r = 0; r < 4; ++r) es[t][r] = 0.0f;

    __syncthreads();                                    // staging complete

    // ds_read bases: row lr, col16 = lk (frag0) / lk^4 (frag1), un-swizzled
    // via the same XOR; loop-invariant since row&7 == lr&7 for every tile.
    const unsigned char* lp0 = &lds[lr * ROWB + (((lk    ) ^ (lr & 7)) << 4)];
    const unsigned char* lp1 = &lds[lr * ROWB + (((lk ^ 4) ^ (lr & 7)) << 4)];

    const f32x4 zero = {0.f, 0.f, 0.f, 0.f};

    for (int jt = 0; jt < NTILES; ++jt) {
        bf16x8 n0 = *(const bf16x8*)(lp0 + jt * (16 * ROWB));
        bf16x8 n1 = *(const bf16x8*)(lp1 + jt * (16 * ROWB));
        #pragma unroll
        for (int t = 0; t < TT; ++t) {
            f32x4 acc = __builtin_amdgcn_mfma_f32_16x16x32_bf16(a[t][0], n0, zero, 0, 0, 0);
            acc = __builtin_amdgcn_mfma_f32_16x16x32_bf16(a[t][1], n1, acc, 0, 0, 0);
            #pragma unroll
            for (int r = 0; r < 4; ++r)
                es[t][r] += __builtin_amdgcn_exp2f(acc[r]);
        }
    }

    // es[t][r]: partial over this lane's 16-col slice of row i0+t*16+lk*4+r.
    #pragma unroll
    for (int t = 0; t < TT; ++t)
        #pragma unroll
        for (int r = 0; r < 4; ++r) {
            float v = es[t][r];
            v += __shfl_xor(v, 1, 64);
            v += __shfl_xor(v, 2, 64);
            v += __shfl_xor(v, 4, 64);
            v += __shfl_xor(v, 8, 64);
            es[t][r] = v;
        }

    if (lr == 0) {                                      // lanes 0,16,32,48
        float* pout = partials + (size_t)jc * NROWS + i0;
        #pragma unroll
        for (int t = 0; t < TT; ++t) {
            f32x4 v = {es[t][0], es[t][1], es[t][2], es[t][3]};
            *(f32x4*)(pout + t * 16 + lk * 4) = v;      // rows lk*4..lk*4+3
        }
    }
}

// -------- kernel 3: per-row loss; lane-parallel partial sum (JC==64) -------
__global__ __launch_bounds__(256) void rowloss_kernel(
        const float* __restrict__ A, const float* __restrict__ B,
        const float* __restrict__ partials, float* __restrict__ rowloss) {
    int row  = (blockIdx.x * 256 + threadIdx.x) >> 6;
    int lane = threadIdx.x & 63;
    float a = A[row * DIM + lane];
    float b = B[row * DIM + lane];
    float saa = a * a, sbb = b * b, sab = a * b;
    float S   = partials[(size_t)lane * NROWS + row];   // one chunk per lane
    #pragma unroll
    for (int m = 32; m >= 1; m >>= 1) {
        saa += __shfl_xor(saa, m, 64);
        sbb += __shfl_xor(sbb, m, 64);
        sab += __shfl_xor(sab, m, 64);
        S   += __shfl_xor(S,   m, 64);
    }
    if (lane == 0) {
        float diag = sab * rsqrtf(saa * sbb);           // exact fp32 cos-sim
        rowloss[row] = LN2 * __builtin_amdgcn_logf(S) - diag * INV_T;
    }
}

// -------- kernel 4: deterministic mean over 16384 row losses ---------------
__global__ __launch_bounds__(1024) void mean_kernel(
        const float* __restrict__ rowloss, float* __restrict__ out) {
    float s = 0.f;
    for (int idx = threadIdx.x; idx < NROWS; idx += 1024) s += rowloss[idx];
    __shared__ float red[16];
    #pragma unroll
    for (int m = 32; m >= 1; m >>= 1) s += __shfl_xor(s, m, 64);
    if ((threadIdx.x & 63) == 0) red[threadIdx.x >> 6] = s;
    __syncthreads();
    if (threadIdx.x < 16) {
        float t = red[threadIdx.x];
        #pragma unroll
        for (int m = 8; m >= 1; m >>= 1) t += __shfl_xor(t, m, 16);
        if (threadIdx.x == 0) out[0] = t * (1.0f / NROWS);
    }
}

extern "C" void kernel_launch(void* const* d_in, const int* in_sizes, int n_in,
                              void* d_out, int out_size, void* d_ws, size_t ws_size,
                              hipStream_t stream) {
    const float* A  = (const float*)d_in[0];
    const float* Bm = (const float*)d_in[1];
    float* out = (float*)d_out;

    unsigned short* Ab = (unsigned short*)d_ws;                 // 2 MiB
    unsigned short* Bb = Ab + (size_t)NROWS * DIM;              // 2 MiB
    float* partials    = (float*)(Bb + (size_t)NROWS * DIM);    // 4 MiB
    float* rowloss     = partials + (size_t)JC * NROWS;         // 64 KiB

    nrm_bf16_kernel<<<2 * NROWS / 4, 256, 0, stream>>>(A, Bm, Ab, Bb);
    simexp_kernel<<<(NROWS / BROWS) * JC, NWAVE * 64, 0, stream>>>(Ab, Bb, partials);
    rowloss_kernel<<<NROWS / 4, 256, 0, stream>>>(A, Bm, partials, rowloss);
    mean_kernel<<<1, 1024, 0, stream>>>(rowloss, out);
}

// Round 9
// 67.483 us; speedup vs baseline: 3.6497x; 1.2322x over previous
//
#include <hip/hip_runtime.h>
#include <math.h>

// ContrastiveLoss: B=16384, D=64, fp32 in, scalar fp32 out.
// loss_i = logsumexp_j(sim[i,j]) - sim[i,i];  out = mean_i(loss_i)
// sim = normalize_rows(A) @ normalize_rows(B)^T / 0.07
//
// Round 9: recombine proven pieces. R5 (TT=4 + acc ping-pong, 124 VGPR) = 65us;
// R8 (TT=4, no ping-pong, 8 waves, 96 VGPR) = 70.5us -> the ping-pong matters
// on the LDS path (breaks MFMA->exp RAW chains across iterations). VALU-cycle
// fit across R5/R8 gives exp2 ~8cyc/wave-instr -> chip exp floor ~14us, VALU
// floor ~20us. This round: TT=2 (a=16,es=8,accp=8,n=8 regs -> target <=64
// VGPR = 8 waves/SIMD by the m69 pool formula) + NWAVE=8 + ping-pong, so
// residency x duty finally covers the latency. Staging/swizzle unchanged.

#define NROWS 16384
#define DIM 64
#define INV_T 14.285714285714286f           // 1/0.07
#define LOG2E 1.44269504088896340736f
#define LN2   0.69314718055994530942f
#define SCALE (INV_T * LOG2E)               // fold 1/T and log2(e) into A

#define JC     64                           // j-chunks; == wavefront size
#define JPC    (NROWS / JC)                 // 256 j per chunk
#define NTILES (JPC / 16)                   // 16 B-tiles per chunk
#define TT     2                            // A row-tiles per wave (32 rows)
#define WR     (TT * 16)                    // 32 rows per wave
#define NWAVE  8                            // waves per block
#define BROWS  (NWAVE * WR)                 // 256 rows per block
#define ROWB   (DIM * 2)                    // 128 bytes per bf16 row
#define LDSB   (JPC * ROWB)                 // 32 KiB

typedef __attribute__((ext_vector_type(8))) short bf16x8;  // 8 bf16 = 4 VGPRs
typedef __attribute__((ext_vector_type(4))) float f32x4;

static __device__ __forceinline__ unsigned short f2bf(float f) {
    unsigned int u = __float_as_uint(f);
    unsigned int r = (u + 0x7fffu + ((u >> 16) & 1u)) >> 16;   // RNE
    return (unsigned short)r;
}

// ------- kernel 1: normalize rows of BOTH inputs -> bf16 (A pre-scaled) ----
__global__ __launch_bounds__(256) void nrm_bf16_kernel(
        const float* __restrict__ A, const float* __restrict__ B,
        unsigned short* __restrict__ Ab, unsigned short* __restrict__ Bb) {
    int wid  = (blockIdx.x * 256 + threadIdx.x) >> 6;   // 0..2*NROWS-1
    int lane = threadIdx.x & 63;
    const float* in;
    unsigned short* out;
    float scale;
    int row;
    if (wid < NROWS) { in = A; out = Ab; scale = SCALE; row = wid; }
    else             { in = B; out = Bb; scale = 1.0f;  row = wid - NROWS; }
    float x  = in[row * DIM + lane];
    float ss = x * x;
    #pragma unroll
    for (int m = 32; m >= 1; m >>= 1) ss += __shfl_xor(ss, m, 64);
    out[row * DIM + lane] = f2bf(x * rsqrtf(ss) * scale);
}

// -------- kernel 2: LDS-staged MFMA sim tiles + exp2 row-sum partials ------
__global__ __launch_bounds__(NWAVE * 64) void simexp_kernel(
        const unsigned short* __restrict__ Ab,
        const unsigned short* __restrict__ Bb,
        float* __restrict__ partials) {
    __shared__ __align__(1024) unsigned char lds[LDSB];
    const int lane = threadIdx.x & 63;
    const int wid  = threadIdx.x >> 6;                  // wave in block
    const int jc   = blockIdx.x & (JC - 1);
    const int rb   = blockIdx.x / JC;
    const int i0   = rb * BROWS + wid * WR;             // wave's first A row
    const int lr   = lane & 15;                         // fragment row/col
    const int lk   = lane >> 4;                         // k-group (x8 bf16)

    // ---- stage B chunk: linear LDS dest, XOR-permuted global source ------
    // LDS(row, col16) holds global(row, col16 ^ (row&7)); each instr covers
    // 8 rows (1 KiB), so row&7 == lane>>3 inside the instr.  (validated r5)
    const unsigned char* gB = (const unsigned char*)Bb + (size_t)jc * JPC * ROWB;
    const int perm = ((lane >> 3) << 7) | ((((lane & 7) ^ (lane >> 3))) << 4);
    #pragma unroll
    for (int i = 0; i < LDSB / 1024 / NWAVE; ++i) {     // 4 slabs per wave
        const int off = (wid * (LDSB / 1024 / NWAVE) + i) * 1024;
        __builtin_amdgcn_global_load_lds(
            (const __attribute__((address_space(1))) void*)(gB + off + perm),
            (__attribute__((address_space(3))) void*)(&lds[off]),
            16, 0, 0);
    }

    // ---- A fragments (global/L2 loads overlap the staging latency) -------
    bf16x8 a[TT][2];
    #pragma unroll
    for (int t = 0; t < TT; ++t) {
        const unsigned short* ap = Ab + (size_t)(i0 + t * 16 + lr) * DIM + lk * 8;
        a[t][0] = *(const bf16x8*)(ap);
        a[t][1] = *(const bf16x8*)(ap + 32);
    }

    float es[TT][4];
    #pragma unroll
    for (int t = 0; t < TT; ++t)
        #pragma unroll
        for (int r = 0; r < 4; ++r) es[t][r] = 0.0f;

    __syncthreads();                                    // staging complete

    // ds_read bases: row lr, col16 = lk (frag0) / lk^4 (frag1), un-swizzled
    // via the same XOR; loop-invariant since row&7 == lr&7 for every tile.
    const unsigned char* lp0 = &lds[lr * ROWB + (((lk    ) ^ (lr & 7)) << 4)];
    const unsigned char* lp1 = &lds[lr * ROWB + (((lk ^ 4) ^ (lr & 7)) << 4)];

    const f32x4 zero = {0.f, 0.f, 0.f, 0.f};

    // ---- prologue: tile 0 -> accp ----
    bf16x8 c0 = *(const bf16x8*)(lp0);
    bf16x8 c1 = *(const bf16x8*)(lp1);
    f32x4 accp[TT];
    #pragma unroll
    for (int t = 0; t < TT; ++t) {
        accp[t] = __builtin_amdgcn_mfma_f32_16x16x32_bf16(a[t][0], c0, zero, 0, 0, 0);
        accp[t] = __builtin_amdgcn_mfma_f32_16x16x32_bf16(a[t][1], c1, accp[t], 0, 0, 0);
    }

    // ---- steady state: ds_read(jt) | exp(jt-1) | MFMA(jt) ----
    for (int jt = 1; jt < NTILES; ++jt) {
        bf16x8 n0 = *(const bf16x8*)(lp0 + jt * (16 * ROWB));
        bf16x8 n1 = *(const bf16x8*)(lp1 + jt * (16 * ROWB));
        #pragma unroll
        for (int t = 0; t < TT; ++t)
            #pragma unroll
            for (int r = 0; r < 4; ++r)
                es[t][r] += __builtin_amdgcn_exp2f(accp[t][r]);
        #pragma unroll
        for (int t = 0; t < TT; ++t) {
            accp[t] = __builtin_amdgcn_mfma_f32_16x16x32_bf16(a[t][0], n0, zero, 0, 0, 0);
            accp[t] = __builtin_amdgcn_mfma_f32_16x16x32_bf16(a[t][1], n1, accp[t], 0, 0, 0);
        }
    }
    // ---- epilogue: exp of last tile ----
    #pragma unroll
    for (int t = 0; t < TT; ++t)
        #pragma unroll
        for (int r = 0; r < 4; ++r)
            es[t][r] += __builtin_amdgcn_exp2f(accp[t][r]);

    // es[t][r]: partial over this lane's 16-col slice of row i0+t*16+lk*4+r.
    #pragma unroll
    for (int t = 0; t < TT; ++t)
        #pragma unroll
        for (int r = 0; r < 4; ++r) {
            float v = es[t][r];
            v += __shfl_xor(v, 1, 64);
            v += __shfl_xor(v, 2, 64);
            v += __shfl_xor(v, 4, 64);
            v += __shfl_xor(v, 8, 64);
            es[t][r] = v;
        }

    if (lr == 0) {                                      // lanes 0,16,32,48
        float* pout = partials + (size_t)jc * NROWS + i0;
        #pragma unroll
        for (int t = 0; t < TT; ++t) {
            f32x4 v = {es[t][0], es[t][1], es[t][2], es[t][3]};
            *(f32x4*)(pout + t * 16 + lk * 4) = v;      // rows lk*4..lk*4+3
        }
    }
}

// -------- kernel 3: per-row loss; lane-parallel partial sum (JC==64) -------
__global__ __launch_bounds__(256) void rowloss_kernel(
        const float* __restrict__ A, const float* __restrict__ B,
        const float* __restrict__ partials, float* __restrict__ rowloss) {
    int row  = (blockIdx.x * 256 + threadIdx.x) >> 6;
    int lane = threadIdx.x & 63;
    float a = A[row * DIM + lane];
    float b = B[row * DIM + lane];
    float saa = a * a, sbb = b * b, sab = a * b;
    float S   = partials[(size_t)lane * NROWS + row];   // one chunk per lane
    #pragma unroll
    for (int m = 32; m >= 1; m >>= 1) {
        saa += __shfl_xor(saa, m, 64);
        sbb += __shfl_xor(sbb, m, 64);
        sab += __shfl_xor(sab, m, 64);
        S   += __shfl_xor(S,   m, 64);
    }
    if (lane == 0) {
        float diag = sab * rsqrtf(saa * sbb);           // exact fp32 cos-sim
        rowloss[row] = LN2 * __builtin_amdgcn_logf(S) - diag * INV_T;
    }
}

// -------- kernel 4: deterministic mean over 16384 row losses ---------------
__global__ __launch_bounds__(1024) void mean_kernel(
        const float* __restrict__ rowloss, float* __restrict__ out) {
    float s = 0.f;
    for (int idx = threadIdx.x; idx < NROWS; idx += 1024) s += rowloss[idx];
    __shared__ float red[16];
    #pragma unroll
    for (int m = 32; m >= 1; m >>= 1) s += __shfl_xor(s, m, 64);
    if ((threadIdx.x & 63) == 0) red[threadIdx.x >> 6] = s;
    __syncthreads();
    if (threadIdx.x < 16) {
        float t = red[threadIdx.x];
        #pragma unroll
        for (int m = 8; m >= 1; m >>= 1) t += __shfl_xor(t, m, 16);
        if (threadIdx.x == 0) out[0] = t * (1.0f / NROWS);
    }
}

extern "C" void kernel_launch(void* const* d_in, const int* in_sizes, int n_in,
                              void* d_out, int out_size, void* d_ws, size_t ws_size,
                              hipStream_t stream) {
    const float* A  = (const float*)d_in[0];
    const float* Bm = (const float*)d_in[1];
    float* out = (float*)d_out;

    unsigned short* Ab = (unsigned short*)d_ws;                 // 2 MiB
    unsigned short* Bb = Ab + (size_t)NROWS * DIM;              // 2 MiB
    float* partials    = (float*)(Bb + (size_t)NROWS * DIM);    // 4 MiB
    float* rowloss     = partials + (size_t)JC * NROWS;         // 64 KiB

    nrm_bf16_kernel<<<2 * NROWS / 4, 256, 0, stream>>>(A, Bm, Ab, Bb);
    simexp_kernel<<<(NROWS / BROWS) * JC, NWAVE * 64, 0, stream>>>(Ab, Bb, partials);
    rowloss_kernel<<<NROWS / 4, 256, 0, stream>>>(A, Bm, partials, rowloss);
    mean_kernel<<<1, 1024, 0, stream>>>(rowloss, out);
}